// Round 1
// baseline (601.365 us; speedup 1.0000x reference)
//
#include <hip/hip_runtime.h>
#include <cstddef>
#include <cstdint>

// Problem constants (match reference)
#define DMODEL 1024
#define DI     2048      // D_INNER
#define LSEQ   2048
#define NB     2
#define DSTATE 16
#define DTRANK 64
#define NXP    96        // DT_RANK + 2*D_STATE
#define MROWS  (NB*LSEQ) // 4096 GEMM rows
#define CHUNKS 32
#define LC     (LSEQ/CHUNKS)   // 64

typedef __attribute__((ext_vector_type(8))) short bf16x8;
typedef __attribute__((ext_vector_type(8))) unsigned short u16x8;
typedef __attribute__((ext_vector_type(4))) float f32x4;

__device__ __forceinline__ float silu_f(float v) {
  return v / (1.f + __expf(-v));
}
__device__ __forceinline__ float softplus_f(float v) {
  return (v > 20.f) ? v : log1pf(__expf(v));
}
__device__ __forceinline__ unsigned short f2bf(float f) {   // RNE
  unsigned u = __float_as_uint(f);
  unsigned r = (u + 0x7FFFu + ((u >> 16) & 1u)) >> 16;
  return (unsigned short)r;
}
__device__ __forceinline__ float bf2f(unsigned short h) {
  return __uint_as_float(((unsigned)h) << 16);
}
__device__ __forceinline__ void gl2lds16(const void* g, void* l) {
  __builtin_amdgcn_global_load_lds(
      (const __attribute__((address_space(1))) void*)g,
      (__attribute__((address_space(3))) void*)l, 16, 0, 0);
}

// Prep: split W_in/W_dt/W_out to bf16 hi/lo (RNE) + zero xp and out.
// One dispatch; block ranges select the job.
__global__ __launch_bounds__(256)
void prep_kernel(const float* __restrict__ W_in, const float* __restrict__ W_dt,
                 const float* __restrict__ W_out,
                 unsigned short* __restrict__ Whi, unsigned short* __restrict__ Wlo,
                 unsigned short* __restrict__ wdhi, unsigned short* __restrict__ wdlo,
                 unsigned short* __restrict__ Wohi, unsigned short* __restrict__ Wolo,
                 float* __restrict__ xp, float* __restrict__ out) {
  const int N_WIN  = 2*DI*DMODEL/4;   // 1,048,576 float4
  const int N_WDT  = DI*DTRANK/4;     //    32,768
  const int N_WOUT = DMODEL*DI/4;     //   524,288
  const int N_XP   = MROWS*NXP/4;     //    98,304
  const int N_OUT  = MROWS*DMODEL/4;  // 1,048,576
  int i = blockIdx.x * 256 + threadIdx.x;
  const float* src = nullptr;
  unsigned short *hi = nullptr, *lo = nullptr;
  if (i < N_WIN)  { src = W_in;  hi = Whi;  lo = Wlo;  }
  else {
    i -= N_WIN;
    if (i < N_WDT)  { src = W_dt;  hi = wdhi; lo = wdlo; }
    else {
      i -= N_WDT;
      if (i < N_WOUT) { src = W_out; hi = Wohi; lo = Wolo; }
      else {
        i -= N_WOUT;
        if (i < N_XP) { ((float4*)xp)[i] = make_float4(0.f,0.f,0.f,0.f); }
        else {
          i -= N_XP;
          if (i < N_OUT) ((float4*)out)[i] = make_float4(0.f,0.f,0.f,0.f);
        }
        return;
      }
    }
  }
  float4 v = ((const float4*)src)[i];
  ushort4 h, l;
  h.x = f2bf(v.x); h.y = f2bf(v.y); h.z = f2bf(v.z); h.w = f2bf(v.w);
  l.x = f2bf(v.x - bf2f(h.x)); l.y = f2bf(v.y - bf2f(h.y));
  l.z = f2bf(v.z - bf2f(h.z)); l.w = f2bf(v.w - bf2f(h.w));
  ((ushort4*)hi)[i] = h; ((ushort4*)lo)[i] = l;
}

// C[m,n] = act( sum_k A[m,k]*B[n,k] ), A fp32 (in-kernel hi/lo split),
// B pre-split bf16 hi/lo. bf16x3: AhBh + AhBl + AlBh.
// 128x128 tile, 4 waves, BK=32, 48 MFMA per barrier pair.
// A: global fp32 loads -> register cvt (truncation split, err 2^-16) ->
//    ds_write_b128 into swizzled layout; next-K A prefetched during MFMA.
// B: global_load_lds 16B, swizzle c' = c ^ ((row>>1)&3) (2-way = free, m136).
// RACE FIX (r1): explicit s_waitcnt vmcnt(0) pinned BETWEEN the gl2lds16
// issues and the A-prefetch issues. At that point the only outstanding vmem
// ops are the 4 gl2lds16 (prologue/prev-prefetch loads were consumed by the
// cvt / ac=an copy), so this is the minimal drain that guarantees Bh/Bl are
// complete at the barrier regardless of what waitcnt the compiler elects,
// while leaving the A-prefetch free to stay in flight across the barrier.
// Dual-output cols [0,NC)->C0, [NC,2NC)->C1. Split-K via blockIdx.z.
// ACT=1: softplus(v + bias[col]).
template<bool ATOMIC, int ACT>
__global__ __launch_bounds__(256)
void gemm_a32_bf16x3(const float* __restrict__ A, int lda,
                     const unsigned short* __restrict__ Bhi, const unsigned short* __restrict__ Blo,
                     const float* __restrict__ bias,
                     float* __restrict__ C0, float* __restrict__ C1,
                     int NC, int K, int klen) {
  __shared__ __align__(16) unsigned short Ah[128 * 32];
  __shared__ __align__(16) unsigned short Al[128 * 32];
  __shared__ __align__(16) unsigned short Bh[128 * 32];
  __shared__ __align__(16) unsigned short Bl[128 * 32];
  const int tid  = threadIdx.x;
  const int lane = tid & 63;
  const int wv   = tid >> 6;
  const int wm   = wv >> 1, wn = wv & 1;
  const int quad = lane >> 4, lr = lane & 15;
  const int bm = blockIdx.y * 128, bn = blockIdx.x * 128;
  const int kbeg = blockIdx.z * klen, kend = kbeg + klen;

  // A staging: thread -> (row ar, k-half ahalf); writes 2 granules/plane.
  const int ar = tid >> 1;            // 0..127
  const int ahalf = tid & 1;          // k offset 16*ahalf
  const int asw = (ar >> 1) & 3;
  const int aw0 = (ar * 4 + ((ahalf * 2)     ^ asw)) << 4;   // LDS bytes
  const int aw1 = (ar * 4 + ((ahalf * 2 + 1) ^ asw)) << 4;
  const float* aptr = A + (size_t)(bm + ar) * lda + ahalf * 16;

  // B staging decode
  int bOff[2], ldsO[2];
  #pragma unroll
  for (int j = 0; j < 2; ++j) {
    const int s   = (wv * 2 + j) * 64 + lane;
    const int row = s >> 2;
    const int c   = (s & 3) ^ ((row >> 1) & 3);
    bOff[j] = (bn + row) * K + c * 8;
    ldsO[j] = (wv * 2 + j) << 10;
  }
  // Fragment read byte offsets (swizzle-matched)
  int aRd[4], bRd[4];
  #pragma unroll
  for (int i = 0; i < 4; ++i) {
    const int ra = wm * 64 + i * 16 + lr;
    aRd[i] = (ra * 4 + (quad ^ ((ra >> 1) & 3))) << 4;
    const int rb = wn * 64 + i * 16 + lr;
    bRd[i] = (rb * 4 + (quad ^ ((rb >> 1) & 3))) << 4;
  }

  f32x4 acc[4][4];
  #pragma unroll
  for (int i = 0; i < 4; ++i)
    #pragma unroll
    for (int j = 0; j < 4; ++j)
      acc[i][j] = (f32x4){0.f, 0.f, 0.f, 0.f};

  // Prologue: load first A block (16 fp32 per thread)
  float ac[16], an[16];
  #pragma unroll
  for (int q = 0; q < 4; ++q)
    *(float4*)&ac[q * 4] = *(const float4*)(aptr + kbeg + q * 4);

  #pragma unroll 1
  for (int km = kbeg; km < kend; km += 32) {
    // B async staging (issue first)
    #pragma unroll
    for (int j = 0; j < 2; ++j) {
      gl2lds16(Bhi + (size_t)bOff[j] + km, (char*)Bh + ldsO[j]);
      gl2lds16(Blo + (size_t)bOff[j] + km, (char*)Bl + ldsO[j]);
    }
    // Convert current A -> hi/lo, write to LDS (truncation split).
    // This VALU+DS work overlaps the in-flight gl2lds16.
    u16x8 vh[2], vl[2];
    #pragma unroll
    for (int g = 0; g < 2; ++g)
      #pragma unroll
      for (int e = 0; e < 8; ++e) {
        const float v = ac[g * 8 + e];
        const unsigned u = __float_as_uint(v);
        const float rem = v - __uint_as_float(u & 0xFFFF0000u);
        vh[g][e] = (unsigned short)(u >> 16);
        vl[g][e] = (unsigned short)(__float_as_uint(rem) >> 16);
      }
    *(u16x8*)((char*)Ah + aw0) = vh[0];
    *(u16x8*)((char*)Ah + aw1) = vh[1];
    *(u16x8*)((char*)Al + aw0) = vl[0];
    *(u16x8*)((char*)Al + aw1) = vl[1];
    // Drain the 4 gl2lds16 (only outstanding vmem here) BEFORE issuing the
    // A prefetch, so Bh/Bl are guaranteed complete at the barrier and the
    // prefetch can stay in flight.
    asm volatile("s_waitcnt vmcnt(0)" ::: "memory");
    // Prefetch next A block
    if (km + 32 < kend) {
      #pragma unroll
      for (int q = 0; q < 4; ++q)
        *(float4*)&an[q * 4] = *(const float4*)(aptr + km + 32 + q * 4);
    }
    __syncthreads();

    bf16x8 ah[4], al[4], bh[4], bl[4];
    #pragma unroll
    for (int i = 0; i < 4; ++i) {
      ah[i] = *(const bf16x8*)((const char*)Ah + aRd[i]);
      al[i] = *(const bf16x8*)((const char*)Al + aRd[i]);
      bh[i] = *(const bf16x8*)((const char*)Bh + bRd[i]);
      bl[i] = *(const bf16x8*)((const char*)Bl + bRd[i]);
    }
    #pragma unroll
    for (int i = 0; i < 4; ++i)
      #pragma unroll
      for (int j = 0; j < 4; ++j) {
        acc[i][j] = __builtin_amdgcn_mfma_f32_16x16x32_bf16(ah[i], bh[j], acc[i][j], 0, 0, 0);
        acc[i][j] = __builtin_amdgcn_mfma_f32_16x16x32_bf16(ah[i], bl[j], acc[i][j], 0, 0, 0);
        acc[i][j] = __builtin_amdgcn_mfma_f32_16x16x32_bf16(al[i], bh[j], acc[i][j], 0, 0, 0);
      }
    __syncthreads();
    if (km + 32 < kend) {
      #pragma unroll
      for (int e = 0; e < 16; ++e) ac[e] = an[e];
    }
  }

  float* C = C0;
  int bnc = bn;
  if (bn >= NC) { C = C1; bnc = bn - NC; }

  // Epilogue: C/D layout col=lane&15, row=quad*4+reg  [m89-verified]
  #pragma unroll
  for (int i = 0; i < 4; ++i) {
    const int gr = bm + wm * 64 + i * 16 + quad * 4;
    #pragma unroll
    for (int j = 0; j < 4; ++j) {
      const int gc = bnc + wn * 64 + j * 16 + lr;
      float* cp = C + (size_t)gr * NC + gc;
      const float bv = (ACT == 1) ? bias[gc] : 0.f;
      #pragma unroll
      for (int r = 0; r < 4; ++r) {
        float v = acc[i][j][r];
        if (ACT == 1) v = softplus_f(v + bv);
        if (ATOMIC) atomicAdd(&cp[(size_t)r * NC], v);
        else        cp[(size_t)r * NC] = v;
      }
    }
  }
}

// Split-K fp32 GEMM, atomicAdd epilogue (C pre-zeroed). Used for GEMM2 (N=96).
__global__ __launch_bounds__(256)
void gemm_nt_splitk(const float* __restrict__ A, const float* __restrict__ B,
                    float* __restrict__ C,
                    int N, int lda, int ldb, int ldc, int kslice) {
  __shared__ float As[16][132];
  __shared__ float Bs[16][132];
  const int tid = threadIdx.x;
  const int bm = blockIdx.y * 128, bn = blockIdx.x * 128;
  const int kbeg = blockIdx.z * kslice, kend = kbeg + kslice;
  const int r  = tid >> 2;
  const int c4 = (tid & 3) << 2;
  const int ty = tid >> 4, tx = tid & 15;
  float acc[8][8];
  #pragma unroll
  for (int i = 0; i < 8; ++i)
    #pragma unroll
    for (int j = 0; j < 8; ++j) acc[i][j] = 0.f;

  for (int k0 = kbeg; k0 < kend; k0 += 16) {
    float4 a0 = *(const float4*)(A + (size_t)(bm + r) * lda + k0 + c4);
    float4 a1 = *(const float4*)(A + (size_t)(bm + r + 64) * lda + k0 + c4);
    float4 b0 = make_float4(0.f, 0.f, 0.f, 0.f);
    float4 b1 = make_float4(0.f, 0.f, 0.f, 0.f);
    if (bn + r < N)      b0 = *(const float4*)(B + (size_t)(bn + r) * ldb + k0 + c4);
    if (bn + r + 64 < N) b1 = *(const float4*)(B + (size_t)(bn + r + 64) * ldb + k0 + c4);
    As[c4+0][r]    = a0.x; As[c4+1][r]    = a0.y; As[c4+2][r]    = a0.z; As[c4+3][r]    = a0.w;
    As[c4+0][r+64] = a1.x; As[c4+1][r+64] = a1.y; As[c4+2][r+64] = a1.z; As[c4+3][r+64] = a1.w;
    Bs[c4+0][r]    = b0.x; Bs[c4+1][r]    = b0.y; Bs[c4+2][r]    = b0.z; Bs[c4+3][r]    = b0.w;
    Bs[c4+0][r+64] = b1.x; Bs[c4+1][r+64] = b1.y; Bs[c4+2][r+64] = b1.z; Bs[c4+3][r+64] = b1.w;
    __syncthreads();
    #pragma unroll
    for (int k = 0; k < 16; ++k) {
      float4 av0 = *(const float4*)&As[k][ty*4];
      float4 av1 = *(const float4*)&As[k][64 + ty*4];
      float4 bv0 = *(const float4*)&Bs[k][tx*4];
      float4 bv1 = *(const float4*)&Bs[k][64 + tx*4];
      float a[8] = {av0.x, av0.y, av0.z, av0.w, av1.x, av1.y, av1.z, av1.w};
      float b[8] = {bv0.x, bv0.y, bv0.z, bv0.w, bv1.x, bv1.y, bv1.z, bv1.w};
      #pragma unroll
      for (int i = 0; i < 8; ++i)
        #pragma unroll
        for (int j = 0; j < 8; ++j)
          acc[i][j] = fmaf(a[i], b[j], acc[i][j]);
    }
    __syncthreads();
  }
  #pragma unroll
  for (int i = 0; i < 8; ++i) {
    const int m = bm + ty * 4 + (i & 3) + ((i >= 4) ? 64 : 0);
    #pragma unroll
    for (int j = 0; j < 8; ++j) {
      const int n = bn + tx * 4 + (j & 3) + ((j >= 4) ? 64 : 0);
      if (n < N) atomicAdd(&C[(size_t)m * ldc + n], acc[i][j]);
    }
  }
}

// Causal depthwise conv (width 4) + bias + SiLU.  xc2[b,l,d]
__global__ __launch_bounds__(256)
void conv_silu_kernel(const float* __restrict__ xc_raw, const float* __restrict__ cw,
                      const float* __restrict__ cb, float* __restrict__ xc2) {
  const int idx = blockIdx.x * 256 + threadIdx.x;
  const int d = idx & (DI - 1);
  const int l = (idx >> 11) & (LSEQ - 1);
  const int b = idx >> 22;
  float acc = cb[d];
  #pragma unroll
  for (int j = 0; j < 4; ++j) {
    const int ls = l - 3 + j;
    if (ls >= 0)
      acc = fmaf(xc_raw[((size_t)b * LSEQ + ls) * DI + d], cw[d * 4 + j], acc);
  }
  xc2[idx] = silu_f(acc);
}

// ---- Chunked selective scan, serial-state layout ----
__global__ __launch_bounds__(256)
void scan_chunk_kernel(const float* __restrict__ xc2, float* __restrict__ dtb,
                       const float* __restrict__ xp, const float* __restrict__ A_log,
                       float* __restrict__ y_local, float* __restrict__ hloc,
                       float* __restrict__ totdt) {
  __shared__ float sbc[LC][32];   // 8 KB: [t][0:16)=B, [16:32)=C
  const int d = blockIdx.x * 256 + threadIdx.x;
  const int b = blockIdx.y;
  const int c = blockIdx.z;

  float A[DSTATE], h[DSTATE];
  #pragma unroll
  for (int n = 0; n < DSTATE; ++n) {
    A[n] = -__expf(A_log[(size_t)d * DSTATE + n]);
    h[n] = 0.f;
  }

  const float* xpb = xp + ((size_t)b * LSEQ + (size_t)c * LC) * NXP + DTRANK;
  #pragma unroll
  for (int kk = 0; kk < 2; ++kk) {
    const int slot = threadIdx.x + kk * 256;
    const int row = slot >> 3, c4 = (slot & 7) << 2;
    *(float4*)&sbc[row][c4] = *(const float4*)&xpb[(size_t)row * NXP + c4];
  }
  __syncthreads();

  const size_t cbase = ((size_t)b * LSEQ + (size_t)c * LC) * DI + d;
  float cum = 0.f;
  constexpr int U = 4;
  float cdt[U], cx[U];
  #pragma unroll
  for (int u = 0; u < U; ++u) {
    cdt[u] = dtb[cbase + (size_t)u * DI];
    cx[u]  = xc2[cbase + (size_t)u * DI];
  }

  #pragma unroll 1
  for (int g = 0; g < LC; g += U) {
    float ndt[U], nx[U];
    if (g + U < LC) {
      #pragma unroll
      for (int u = 0; u < U; ++u) {
        ndt[u] = dtb[cbase + (size_t)(g + U + u) * DI];
        nx[u]  = xc2[cbase + (size_t)(g + U + u) * DI];
      }
    }
    #pragma unroll
    for (int u = 0; u < U; ++u) {
      const int t = g + u;
      const float dt = cdt[u];
      const float dx = dt * cx[u];
      cum += dt;
      #pragma unroll
      for (int n = 0; n < DSTATE; ++n) {
        const float ab = __expf(dt * A[n]);
        h[n] = fmaf(ab, h[n], dx * sbc[t][n]);
      }
      float p[DSTATE];
      #pragma unroll
      for (int n = 0; n < DSTATE; ++n) p[n] = h[n] * sbc[t][DSTATE + n];
      #pragma unroll
      for (int s = 1; s < DSTATE; s <<= 1)
        #pragma unroll
        for (int n = 0; n < DSTATE; n += 2 * s) p[n] += p[n + s];
      const size_t base = cbase + (size_t)t * DI;
      y_local[base] = p[0];
      dtb[base] = cum;               // overwrite dt with inclusive cumsum
    }
    if (g + U < LC) {
      #pragma unroll
      for (int u = 0; u < U; ++u) { cdt[u] = ndt[u]; cx[u] = nx[u]; }
    }
  }

  const size_t hbase = ((size_t)(b * CHUNKS + c)) * DSTATE * DI + d;
  #pragma unroll
  for (int n = 0; n < DSTATE; ++n) hloc[hbase + (size_t)n * DI] = h[n];
  totdt[((size_t)(b * CHUNKS + c)) * DI + d] = cum;
}

// Pass 2: carry propagation. One thread per (b,n,d); 1-chunk prefetch.
__global__ __launch_bounds__(256)
void scan_carry_kernel(float* __restrict__ hloc, const float* __restrict__ totdt,
                       const float* __restrict__ A_log) {
  const int tid = blockIdx.x * 256 + threadIdx.x;   // NB*DSTATE*DI
  const int d = tid & (DI - 1);
  const int n = (tid >> 11) & 15;
  const int b = tid >> 15;
  const float An = -__expf(A_log[(size_t)d * DSTATE + n]);
  float h = 0.f;
  float le = hloc[((size_t)(b * CHUNKS) * DSTATE + n) * DI + d];
  float td = totdt[(size_t)(b * CHUNKS) * DI + d];
  for (int c = 0; c < CHUNKS; ++c) {
    const size_t ix = ((size_t)(b * CHUNKS + c) * DSTATE + n) * DI + d;
    float nle = 0.f, ntd = 0.f;
    if (c + 1 < CHUNKS) {
      nle = hloc[ix + (size_t)DSTATE * DI];
      ntd = totdt[(size_t)(b * CHUNKS + c + 1) * DI + d];
    }
    hloc[ix] = h;
    h = fmaf(__expf(An * td), h, le);
    le = nle; td = ntd;
  }
}

// Pass 3: correction + epilogue.  hloc layout [b][c][n][d].
__global__ __launch_bounds__(256)
void scan_fix_kernel(const float* __restrict__ xc2, const float* __restrict__ dtb,
                     const float* __restrict__ xp, const float* __restrict__ zbuf,
                     const float* __restrict__ A_log, const float* __restrict__ Dp,
                     const float* __restrict__ hloc, float* __restrict__ y) {
  __shared__ float sA[256 * DSTATE];
  const int tid = threadIdx.x;
  const int idx = blockIdx.x * 256 + tid;
  const int d = idx & (DI - 1);
  const int l = (idx >> 11) & (LSEQ - 1);
  const int b = idx >> 22;
  const int d0 = (blockIdx.x & ((DI / 256) - 1)) * 256;
  for (int i = tid; i < 256 * DSTATE; i += 256)
    sA[i] = -__expf(A_log[(size_t)d0 * DSTATE + i]);
  __syncthreads();

  const int c = l / LC;
  const float cum = dtb[idx];
  const float* hp = hloc + ((size_t)(b * CHUNKS + c)) * DSTATE * DI + d;
  const float4* Ct4 = (const float4*)&xp[((size_t)b * LSEQ + l) * NXP + DTRANK + DSTATE];
  const float* Ar = &sA[(d - d0) * DSTATE];
  float Ct[DSTATE];
  #pragma unroll
  for (int q = 0; q < 4; ++q) {
    const float4 cv = Ct4[q];
    Ct[4*q+0] = cv.x; Ct[4*q+1] = cv.y; Ct[4*q+2] = cv.z; Ct[4*q+3] = cv.w;
  }
  float corr = 0.f;
  #pragma unroll
  for (int n = 0; n < DSTATE; ++n)
    corr = fmaf(__expf(Ar[n] * cum) * hp[(size_t)n * DI], Ct[n], corr);
  const float xv = xc2[idx], zv = zbuf[idx];
  y[idx] = (y[idx] + corr + xv * Dp[d]) * silu_f(zv);
}

extern "C" void kernel_launch(void* const* d_in, const int* in_sizes, int n_in,
                              void* d_out, int out_size, void* d_ws, size_t ws_size,
                              hipStream_t stream) {
  const float* x      = (const float*)d_in[0];
  const float* W_in   = (const float*)d_in[1];
  const float* conv_w = (const float*)d_in[2];
  const float* conv_b = (const float*)d_in[3];
  const float* W_xproj= (const float*)d_in[4];
  const float* W_dt   = (const float*)d_in[5];
  const float* b_dt   = (const float*)d_in[6];
  const float* A_log  = (const float*)d_in[7];
  const float* Dp     = (const float*)d_in[8];
  const float* W_out  = (const float*)d_in[9];
  float* out = (float*)d_out;
  float* ws  = (float*)d_ws;

  // ws layout (floats), ~154 MB:
  //   xc_raw[SEG] | zbuf[SEG] | xc2[SEG] | dtb[SEG] | xp | hloc | totdt | Wo/Wd pools
  // Overlays (time-disjoint): Whi/Wlo (4.2M floats) over dtb — consumed by
  // GEMM1, dtb first written by GEMM3 afterwards. y reuses xc_raw.
  const size_t SEG = (size_t)NB * LSEQ * DI;            // 8,388,608
  float* xc_raw = ws;
  float* zbuf   = ws + SEG;
  float* xc2    = ws + 2 * SEG;
  float* dtb    = ws + 3 * SEG;
  float* xp     = ws + 4 * SEG;                         // 393,216
  float* hloc   = xp + (size_t)MROWS * NXP;             // 2,097,152
  float* totdt  = hloc + (size_t)NB * CHUNKS * DSTATE * DI;  // 131,072
  float* wpool  = totdt + (size_t)NB * CHUNKS * DI;

  unsigned short* Whi = (unsigned short*)dtb;           // overlay (dead until GEMM3)
  unsigned short* Wlo = Whi + (size_t)2 * DI * DMODEL;

  unsigned short* Wohi = (unsigned short*)wpool;        // 2,097,152 ushort
  unsigned short* Wolo = Wohi + (size_t)DMODEL * DI;
  unsigned short* wdhi = Wolo + (size_t)DMODEL * DI;    // 131,072 ushort
  unsigned short* wdlo = wdhi + (size_t)DI * DTRANK;

  float* yb = xc_raw;
  dim3 blk(256);

  // Prep: weight splits + zero xp/out (one dispatch)
  const int prep_blocks = (2*DI*DMODEL/4 + DI*DTRANK/4 + DMODEL*DI/4
                           + MROWS*NXP/4 + MROWS*DMODEL/4) / 256;
  prep_kernel<<<prep_blocks, blk, 0, stream>>>(
      W_in, W_dt, W_out, Whi, Wlo, wdhi, wdlo, Wohi, Wolo, xp, out);

  // GEMM1 fused: [xc | z] = x @ W_in^T  (A=x fp32 in-kernel split; K=1024)
  gemm_a32_bf16x3<false,0><<<dim3(2*DI/128, MROWS/128, 1), blk, 0, stream>>>(
      x, DMODEL, Whi, Wlo, nullptr, xc_raw, zbuf, DI, DMODEL, DMODEL);

  // conv + bias + SiLU
  conv_silu_kernel<<<(NB*LSEQ*DI)/256, blk, 0, stream>>>(xc_raw, conv_w, conv_b, xc2);

  // GEMM2: xp = xc2 @ W_xproj^T  (N=96) — split-K=8 fp32, atomic (xp zeroed in prep)
  gemm_nt_splitk<<<dim3(1, MROWS/128, 8), blk, 0, stream>>>(
      xc2, W_xproj, xp, NXP, DI, DI, NXP, DI/8);

  // GEMM3: dt = softplus(dt_lr @ W_dt^T + b_dt)  (A = xp[:, 0:64], lda=96, K=64)
  gemm_a32_bf16x3<false,1><<<dim3(DI/128, MROWS/128, 1), blk, 0, stream>>>(
      xp, NXP, wdhi, wdlo, b_dt, dtb, dtb, DI, DTRANK, DTRANK);

  // Chunked scan -> yb
  scan_chunk_kernel<<<dim3(DI/256, NB, CHUNKS), blk, 0, stream>>>(
      xc2, dtb, xp, A_log, yb, hloc, totdt);
  scan_carry_kernel<<<(NB*DI*DSTATE)/256, blk, 0, stream>>>(hloc, totdt, A_log);
  scan_fix_kernel<<<(NB*LSEQ*DI)/256, blk, 0, stream>>>(
      xc2, dtb, xp, zbuf, A_log, Dp, hloc, yb);

  // GEMM4: out = y @ W_out^T — A=y fp32 in-kernel split; split-K=2, atomic
  // (out zeroed in prep)
  gemm_a32_bf16x3<true,0><<<dim3(DMODEL/128, MROWS/128, 2), blk, 0, stream>>>(
      yb, DI, Wohi, Wolo, nullptr, out, out, DMODEL, DI, DI/2);
}

// Round 2
// 543.776 us; speedup vs baseline: 1.1059x; 1.1059x over previous
//
#include <hip/hip_runtime.h>
#include <cstddef>
#include <cstdint>

// Problem constants (match reference)
#define DMODEL 1024
#define DI     2048      // D_INNER
#define LSEQ   2048
#define NB     2
#define DSTATE 16
#define DTRANK 64
#define NXP    96        // DT_RANK + 2*D_STATE
#define MROWS  (NB*LSEQ) // 4096 GEMM rows
#define CHUNKS 32
#define LC     (LSEQ/CHUNKS)   // 64

typedef __attribute__((ext_vector_type(8))) short bf16x8;
typedef __attribute__((ext_vector_type(8))) unsigned short u16x8;
typedef __attribute__((ext_vector_type(4))) float f32x4;

__device__ __forceinline__ float silu_f(float v) {
  return v / (1.f + __expf(-v));
}
__device__ __forceinline__ float softplus_f(float v) {
  return (v > 20.f) ? v : log1pf(__expf(v));
}
__device__ __forceinline__ unsigned short f2bf(float f) {   // RNE
  unsigned u = __float_as_uint(f);
  unsigned r = (u + 0x7FFFu + ((u >> 16) & 1u)) >> 16;
  return (unsigned short)r;
}
__device__ __forceinline__ float bf2f(unsigned short h) {
  return __uint_as_float(((unsigned)h) << 16);
}
__device__ __forceinline__ void gl2lds16(const void* g, void* l) {
  __builtin_amdgcn_global_load_lds(
      (const __attribute__((address_space(1))) void*)g,
      (__attribute__((address_space(3))) void*)l, 16, 0, 0);
}

// Prep: split W_in/W_dt/W_out AND x to bf16 hi/lo (RNE) + zero xp and out.
// One dispatch; block ranges select the job.
__global__ __launch_bounds__(256)
void prep_kernel(const float* __restrict__ W_in, const float* __restrict__ W_dt,
                 const float* __restrict__ W_out, const float* __restrict__ x,
                 unsigned short* __restrict__ Whi, unsigned short* __restrict__ Wlo,
                 unsigned short* __restrict__ wdhi, unsigned short* __restrict__ wdlo,
                 unsigned short* __restrict__ Wohi, unsigned short* __restrict__ Wolo,
                 unsigned short* __restrict__ xhi, unsigned short* __restrict__ xlo,
                 float* __restrict__ xp, float* __restrict__ out) {
  const int N_WIN  = 2*DI*DMODEL/4;   // 1,048,576 float4
  const int N_WDT  = DI*DTRANK/4;     //    32,768
  const int N_WOUT = DMODEL*DI/4;     //   524,288
  const int N_X    = MROWS*DMODEL/4;  // 1,048,576
  const int N_XP   = MROWS*NXP/4;     //    98,304
  const int N_OUT  = MROWS*DMODEL/4;  // 1,048,576
  int i = blockIdx.x * 256 + threadIdx.x;
  const float* src = nullptr;
  unsigned short *hi = nullptr, *lo = nullptr;
  if (i < N_WIN)  { src = W_in;  hi = Whi;  lo = Wlo;  }
  else {
    i -= N_WIN;
    if (i < N_WDT)  { src = W_dt;  hi = wdhi; lo = wdlo; }
    else {
      i -= N_WDT;
      if (i < N_WOUT) { src = W_out; hi = Wohi; lo = Wolo; }
      else {
        i -= N_WOUT;
        if (i < N_X) { src = x; hi = xhi; lo = xlo; }
        else {
          i -= N_X;
          if (i < N_XP) { ((float4*)xp)[i] = make_float4(0.f,0.f,0.f,0.f); }
          else {
            i -= N_XP;
            if (i < N_OUT) ((float4*)out)[i] = make_float4(0.f,0.f,0.f,0.f);
          }
          return;
        }
      }
    }
  }
  float4 v = ((const float4*)src)[i];
  ushort4 h, l;
  h.x = f2bf(v.x); h.y = f2bf(v.y); h.z = f2bf(v.z); h.w = f2bf(v.w);
  l.x = f2bf(v.x - bf2f(h.x)); l.y = f2bf(v.y - bf2f(h.y));
  l.z = f2bf(v.z - bf2f(h.z)); l.w = f2bf(v.w - bf2f(h.w));
  ((ushort4*)hi)[i] = h; ((ushort4*)lo)[i] = l;
}

// C[m,n] = act( sum_k A[m,k]*B[n,k] ), bf16x3: AhBh + AhBl + AlBh.
// 128x128 tile, 4 waves, BK=32, 48 MFMA per iter.
// r2: DOUBLE-BUFFERED LDS, single barrier per K-iter, vmcnt(0) drain at
// iter END (staging for t+1 in flight under tile t's ds_read+MFMA phase).
// APRE=1: A pre-split bf16 hi/lo in global, staged via global_load_lds
//         (pure async staging, no VALU cvt). Used by GEMM1 (A = x split in prep).
// APRE=0: A fp32, in-kernel truncation split + ds_write (GEMM3/GEMM4).
// B: global_load_lds 16B, source-swizzled c' = c ^ ((row>>1)&3); reads use
// matching XOR (rule 21: inverse-swz source + swz read, linear LDS dest).
// Dual-output cols [0,NC)->C0, [NC,2NC)->C1. Split-K via blockIdx.z.
// ACT=1: softplus(v + bias[col]).
template<bool ATOMIC, int ACT, bool APRE>
__global__ __launch_bounds__(256)
void gemm_a32_bf16x3(const float* __restrict__ A,
                     const unsigned short* __restrict__ Ahi_g,
                     const unsigned short* __restrict__ Alo_g,
                     int lda,
                     const unsigned short* __restrict__ Bhi, const unsigned short* __restrict__ Blo,
                     const float* __restrict__ bias,
                     float* __restrict__ C0, float* __restrict__ C1,
                     int NC, int K, int klen) {
  // 2 buffers x 128x32 ushorts (8 KB) per plane -> 64 KB total
  __shared__ __align__(16) unsigned short Ah[2 * 128 * 32];
  __shared__ __align__(16) unsigned short Al[2 * 128 * 32];
  __shared__ __align__(16) unsigned short Bh[2 * 128 * 32];
  __shared__ __align__(16) unsigned short Bl[2 * 128 * 32];
  const int tid  = threadIdx.x;
  const int lane = tid & 63;
  const int wv   = tid >> 6;
  const int wm   = wv >> 1, wn = wv & 1;
  const int quad = lane >> 4, lr = lane & 15;
  const int bm = blockIdx.y * 128, bn = blockIdx.x * 128;
  const int kbeg = blockIdx.z * klen;

  // Staging decode: slot s -> (row, swizzled 8-elem column group)
  int bOff[2], aOffp[2], ldsO[2];
  #pragma unroll
  for (int j = 0; j < 2; ++j) {
    const int s   = (wv * 2 + j) * 64 + lane;
    const int row = s >> 2;
    const int c   = (s & 3) ^ ((row >> 1) & 3);
    bOff[j]  = (bn + row) * K + c * 8;
    aOffp[j] = (bm + row) * lda + c * 8;   // used when APRE
    ldsO[j]  = (wv * 2 + j) << 10;
  }
  // A cvt-path staging: thread -> (row ar, k-half ahalf); 2 granules/plane.
  const int ar = tid >> 1;
  const int ahalf = tid & 1;
  const int asw = (ar >> 1) & 3;
  const int aw0 = (ar * 4 + ((ahalf * 2)     ^ asw)) << 4;   // LDS bytes
  const int aw1 = (ar * 4 + ((ahalf * 2 + 1) ^ asw)) << 4;
  const float* aptr = (!APRE) ? (A + (size_t)(bm + ar) * lda + ahalf * 16) : nullptr;

  // Fragment read byte offsets (swizzle-matched)
  int aRd[4], bRd[4];
  #pragma unroll
  for (int i = 0; i < 4; ++i) {
    const int ra = wm * 64 + i * 16 + lr;
    aRd[i] = (ra * 4 + (quad ^ ((ra >> 1) & 3))) << 4;
    const int rb = wn * 64 + i * 16 + lr;
    bRd[i] = (rb * 4 + (quad ^ ((rb >> 1) & 3))) << 4;
  }

  f32x4 acc[4][4];
  #pragma unroll
  for (int i = 0; i < 4; ++i)
    #pragma unroll
    for (int j = 0; j < 4; ++j)
      acc[i][j] = (f32x4){0.f, 0.f, 0.f, 0.f};

  const int nt = klen / 32;
  float ac[16], an[16];

  // ---- Prologue: stage tile 0 into buffer 0 ----
  if constexpr (APRE) {
    #pragma unroll
    for (int j = 0; j < 2; ++j) {
      gl2lds16(Bhi   + (size_t)bOff[j]  + kbeg, (char*)Bh + ldsO[j]);
      gl2lds16(Blo   + (size_t)bOff[j]  + kbeg, (char*)Bl + ldsO[j]);
      gl2lds16(Ahi_g + (size_t)aOffp[j] + kbeg, (char*)Ah + ldsO[j]);
      gl2lds16(Alo_g + (size_t)aOffp[j] + kbeg, (char*)Al + ldsO[j]);
    }
  } else {
    #pragma unroll
    for (int j = 0; j < 2; ++j) {
      gl2lds16(Bhi + (size_t)bOff[j] + kbeg, (char*)Bh + ldsO[j]);
      gl2lds16(Blo + (size_t)bOff[j] + kbeg, (char*)Bl + ldsO[j]);
    }
    #pragma unroll
    for (int q = 0; q < 4; ++q)
      *(float4*)&ac[q * 4] = *(const float4*)(aptr + kbeg + q * 4);
    u16x8 vh[2], vl[2];
    #pragma unroll
    for (int g = 0; g < 2; ++g)
      #pragma unroll
      for (int e = 0; e < 8; ++e) {
        const float v = ac[g * 8 + e];
        const unsigned u = __float_as_uint(v);
        const float rem = v - __uint_as_float(u & 0xFFFF0000u);
        vh[g][e] = (unsigned short)(u >> 16);
        vl[g][e] = (unsigned short)(__float_as_uint(rem) >> 16);
      }
    *(u16x8*)((char*)Ah + aw0) = vh[0];
    *(u16x8*)((char*)Ah + aw1) = vh[1];
    *(u16x8*)((char*)Al + aw0) = vl[0];
    *(u16x8*)((char*)Al + aw1) = vl[1];
    if (nt > 1) {
      #pragma unroll
      for (int q = 0; q < 4; ++q)
        *(float4*)&ac[q * 4] = *(const float4*)(aptr + kbeg + 32 + q * 4);
    }
  }
  asm volatile("s_waitcnt vmcnt(0)" ::: "memory");
  __syncthreads();

  int cur = 0;
  #pragma unroll 1
  for (int t = 0; t < nt; ++t) {
    const int km = kbeg + t * 32;
    // ---- stage tile t+1 into the other buffer ----
    if (t + 1 < nt) {
      const int nb = (cur ^ 1) * 8192;   // bytes
      if constexpr (APRE) {
        #pragma unroll
        for (int j = 0; j < 2; ++j) {
          gl2lds16(Bhi   + (size_t)bOff[j]  + km + 32, (char*)Bh + nb + ldsO[j]);
          gl2lds16(Blo   + (size_t)bOff[j]  + km + 32, (char*)Bl + nb + ldsO[j]);
          gl2lds16(Ahi_g + (size_t)aOffp[j] + km + 32, (char*)Ah + nb + ldsO[j]);
          gl2lds16(Alo_g + (size_t)aOffp[j] + km + 32, (char*)Al + nb + ldsO[j]);
        }
      } else {
        #pragma unroll
        for (int j = 0; j < 2; ++j) {
          gl2lds16(Bhi + (size_t)bOff[j] + km + 32, (char*)Bh + nb + ldsO[j]);
          gl2lds16(Blo + (size_t)bOff[j] + km + 32, (char*)Bl + nb + ldsO[j]);
        }
        // cvt A tile t+1 (in ac) -> hi/lo, write into buffer nb
        u16x8 vh[2], vl[2];
        #pragma unroll
        for (int g = 0; g < 2; ++g)
          #pragma unroll
          for (int e = 0; e < 8; ++e) {
            const float v = ac[g * 8 + e];
            const unsigned u = __float_as_uint(v);
            const float rem = v - __uint_as_float(u & 0xFFFF0000u);
            vh[g][e] = (unsigned short)(u >> 16);
            vl[g][e] = (unsigned short)(__float_as_uint(rem) >> 16);
          }
        *(u16x8*)((char*)Ah + nb + aw0) = vh[0];
        *(u16x8*)((char*)Ah + nb + aw1) = vh[1];
        *(u16x8*)((char*)Al + nb + aw0) = vl[0];
        *(u16x8*)((char*)Al + nb + aw1) = vl[1];
        if (t + 2 < nt) {
          #pragma unroll
          for (int q = 0; q < 4; ++q)
            *(float4*)&an[q * 4] = *(const float4*)(aptr + km + 64 + q * 4);
        }
      }
    }
    // ---- compute tile t from buffer cur ----
    const int cb = cur * 8192;
    bf16x8 ah[4], al[4], bh[4], bl[4];
    #pragma unroll
    for (int i = 0; i < 4; ++i) {
      ah[i] = *(const bf16x8*)((const char*)Ah + cb + aRd[i]);
      al[i] = *(const bf16x8*)((const char*)Al + cb + aRd[i]);
      bh[i] = *(const bf16x8*)((const char*)Bh + cb + bRd[i]);
      bl[i] = *(const bf16x8*)((const char*)Bl + cb + bRd[i]);
    }
    #pragma unroll
    for (int i = 0; i < 4; ++i)
      #pragma unroll
      for (int j = 0; j < 4; ++j) {
        acc[i][j] = __builtin_amdgcn_mfma_f32_16x16x32_bf16(ah[i], bh[j], acc[i][j], 0, 0, 0);
        acc[i][j] = __builtin_amdgcn_mfma_f32_16x16x32_bf16(ah[i], bl[j], acc[i][j], 0, 0, 0);
        acc[i][j] = __builtin_amdgcn_mfma_f32_16x16x32_bf16(al[i], bh[j], acc[i][j], 0, 0, 0);
      }
    if (t + 1 < nt) {
      // Drain tile t+1's staging loads (issued one compute-phase ago),
      // then one barrier; flip buffers.
      asm volatile("s_waitcnt vmcnt(0)" ::: "memory");
      __syncthreads();
      if constexpr (!APRE) {
        if (t + 2 < nt) {
          #pragma unroll
          for (int e = 0; e < 16; ++e) ac[e] = an[e];
        }
      }
      cur ^= 1;
    }
  }

  float* C = C0;
  int bnc = bn;
  if (bn >= NC) { C = C1; bnc = bn - NC; }

  // Epilogue: C/D layout col=lane&15, row=quad*4+reg  [m89-verified]
  #pragma unroll
  for (int i = 0; i < 4; ++i) {
    const int gr = bm + wm * 64 + i * 16 + quad * 4;
    #pragma unroll
    for (int j = 0; j < 4; ++j) {
      const int gc = bnc + wn * 64 + j * 16 + lr;
      float* cp = C + (size_t)gr * NC + gc;
      const float bv = (ACT == 1) ? bias[gc] : 0.f;
      #pragma unroll
      for (int r = 0; r < 4; ++r) {
        float v = acc[i][j][r];
        if (ACT == 1) v = softplus_f(v + bv);
        if (ATOMIC) atomicAdd(&cp[(size_t)r * NC], v);
        else        cp[(size_t)r * NC] = v;
      }
    }
  }
}

// Split-K fp32 GEMM, atomicAdd epilogue (C pre-zeroed). Used for GEMM2 (N=96).
__global__ __launch_bounds__(256)
void gemm_nt_splitk(const float* __restrict__ A, const float* __restrict__ B,
                    float* __restrict__ C,
                    int N, int lda, int ldb, int ldc, int kslice) {
  __shared__ float As[16][132];
  __shared__ float Bs[16][132];
  const int tid = threadIdx.x;
  const int bm = blockIdx.y * 128, bn = blockIdx.x * 128;
  const int kbeg = blockIdx.z * kslice, kend = kbeg + kslice;
  const int r  = tid >> 2;
  const int c4 = (tid & 3) << 2;
  const int ty = tid >> 4, tx = tid & 15;
  float acc[8][8];
  #pragma unroll
  for (int i = 0; i < 8; ++i)
    #pragma unroll
    for (int j = 0; j < 8; ++j) acc[i][j] = 0.f;

  for (int k0 = kbeg; k0 < kend; k0 += 16) {
    float4 a0 = *(const float4*)(A + (size_t)(bm + r) * lda + k0 + c4);
    float4 a1 = *(const float4*)(A + (size_t)(bm + r + 64) * lda + k0 + c4);
    float4 b0 = make_float4(0.f, 0.f, 0.f, 0.f);
    float4 b1 = make_float4(0.f, 0.f, 0.f, 0.f);
    if (bn + r < N)      b0 = *(const float4*)(B + (size_t)(bn + r) * ldb + k0 + c4);
    if (bn + r + 64 < N) b1 = *(const float4*)(B + (size_t)(bn + r + 64) * ldb + k0 + c4);
    As[c4+0][r]    = a0.x; As[c4+1][r]    = a0.y; As[c4+2][r]    = a0.z; As[c4+3][r]    = a0.w;
    As[c4+0][r+64] = a1.x; As[c4+1][r+64] = a1.y; As[c4+2][r+64] = a1.z; As[c4+3][r+64] = a1.w;
    Bs[c4+0][r]    = b0.x; Bs[c4+1][r]    = b0.y; Bs[c4+2][r]    = b0.z; Bs[c4+3][r]    = b0.w;
    Bs[c4+0][r+64] = b1.x; Bs[c4+1][r+64] = b1.y; Bs[c4+2][r+64] = b1.z; Bs[c4+3][r+64] = b1.w;
    __syncthreads();
    #pragma unroll
    for (int k = 0; k < 16; ++k) {
      float4 av0 = *(const float4*)&As[k][ty*4];
      float4 av1 = *(const float4*)&As[k][64 + ty*4];
      float4 bv0 = *(const float4*)&Bs[k][tx*4];
      float4 bv1 = *(const float4*)&Bs[k][64 + tx*4];
      float a[8] = {av0.x, av0.y, av0.z, av0.w, av1.x, av1.y, av1.z, av1.w};
      float b[8] = {bv0.x, bv0.y, bv0.z, bv0.w, bv1.x, bv1.y, bv1.z, bv1.w};
      #pragma unroll
      for (int i = 0; i < 8; ++i)
        #pragma unroll
        for (int j = 0; j < 8; ++j)
          acc[i][j] = fmaf(a[i], b[j], acc[i][j]);
    }
    __syncthreads();
  }
  #pragma unroll
  for (int i = 0; i < 8; ++i) {
    const int m = bm + ty * 4 + (i & 3) + ((i >= 4) ? 64 : 0);
    #pragma unroll
    for (int j = 0; j < 8; ++j) {
      const int n = bn + tx * 4 + (j & 3) + ((j >= 4) ? 64 : 0);
      if (n < N) atomicAdd(&C[(size_t)m * ldc + n], acc[i][j]);
    }
  }
}

// Causal depthwise conv (width 4) + bias + SiLU.  4 consecutive l per thread.
__global__ __launch_bounds__(256)
void conv_silu_kernel(const float* __restrict__ xc_raw, const float* __restrict__ cw,
                      const float* __restrict__ cb, float* __restrict__ xc2) {
  const int tid = blockIdx.x * 256 + threadIdx.x;   // NB*(LSEQ/4)*DI threads
  const int d  = tid & (DI - 1);
  const int lt = (tid >> 11) & (LSEQ / 4 - 1);
  const int b  = tid >> 20;
  const int l0 = lt << 2;
  const float4 w = *(const float4*)(cw + d * 4);
  const float bias = cb[d];
  const long long rowb = ((long long)b * LSEQ + l0) * DI + d;
  float v[7];
  #pragma unroll
  for (int j = 0; j < 7; ++j) {
    const int ls = l0 - 3 + j;
    v[j] = (ls >= 0) ? xc_raw[rowb + (long long)(j - 3) * DI] : 0.f;
  }
  #pragma unroll
  for (int t = 0; t < 4; ++t) {
    float acc = fmaf(w.x, v[t], bias);
    acc = fmaf(w.y, v[t + 1], acc);
    acc = fmaf(w.z, v[t + 2], acc);
    acc = fmaf(w.w, v[t + 3], acc);
    xc2[rowb + (long long)t * DI] = silu_f(acc);
  }
}

// ---- Chunked selective scan, serial-state layout ----
__global__ __launch_bounds__(256)
void scan_chunk_kernel(const float* __restrict__ xc2, float* __restrict__ dtb,
                       const float* __restrict__ xp, const float* __restrict__ A_log,
                       float* __restrict__ y_local, float* __restrict__ hloc,
                       float* __restrict__ totdt) {
  __shared__ float sbc[LC][32];   // 8 KB: [t][0:16)=B, [16:32)=C
  const int d = blockIdx.x * 256 + threadIdx.x;
  const int b = blockIdx.y;
  const int c = blockIdx.z;

  float A[DSTATE], h[DSTATE];
  #pragma unroll
  for (int n = 0; n < DSTATE; ++n) {
    A[n] = -__expf(A_log[(size_t)d * DSTATE + n]);
    h[n] = 0.f;
  }

  const float* xpb = xp + ((size_t)b * LSEQ + (size_t)c * LC) * NXP + DTRANK;
  #pragma unroll
  for (int kk = 0; kk < 2; ++kk) {
    const int slot = threadIdx.x + kk * 256;
    const int row = slot >> 3, c4 = (slot & 7) << 2;
    *(float4*)&sbc[row][c4] = *(const float4*)&xpb[(size_t)row * NXP + c4];
  }
  __syncthreads();

  const size_t cbase = ((size_t)b * LSEQ + (size_t)c * LC) * DI + d;
  float cum = 0.f;
  constexpr int U = 4;
  float cdt[U], cx[U];
  #pragma unroll
  for (int u = 0; u < U; ++u) {
    cdt[u] = dtb[cbase + (size_t)u * DI];
    cx[u]  = xc2[cbase + (size_t)u * DI];
  }

  #pragma unroll 1
  for (int g = 0; g < LC; g += U) {
    float ndt[U], nx[U];
    if (g + U < LC) {
      #pragma unroll
      for (int u = 0; u < U; ++u) {
        ndt[u] = dtb[cbase + (size_t)(g + U + u) * DI];
        nx[u]  = xc2[cbase + (size_t)(g + U + u) * DI];
      }
    }
    #pragma unroll
    for (int u = 0; u < U; ++u) {
      const int t = g + u;
      const float dt = cdt[u];
      const float dx = dt * cx[u];
      cum += dt;
      #pragma unroll
      for (int n = 0; n < DSTATE; ++n) {
        const float ab = __expf(dt * A[n]);
        h[n] = fmaf(ab, h[n], dx * sbc[t][n]);
      }
      float p[DSTATE];
      #pragma unroll
      for (int n = 0; n < DSTATE; ++n) p[n] = h[n] * sbc[t][DSTATE + n];
      #pragma unroll
      for (int s = 1; s < DSTATE; s <<= 1)
        #pragma unroll
        for (int n = 0; n < DSTATE; n += 2 * s) p[n] += p[n + s];
      const size_t base = cbase + (size_t)t * DI;
      y_local[base] = p[0];
      dtb[base] = cum;               // overwrite dt with inclusive cumsum
    }
    if (g + U < LC) {
      #pragma unroll
      for (int u = 0; u < U; ++u) { cdt[u] = ndt[u]; cx[u] = nx[u]; }
    }
  }

  const size_t hbase = ((size_t)(b * CHUNKS + c)) * DSTATE * DI + d;
  #pragma unroll
  for (int n = 0; n < DSTATE; ++n) hloc[hbase + (size_t)n * DI] = h[n];
  totdt[((size_t)(b * CHUNKS + c)) * DI + d] = cum;
}

// Pass 2: carry propagation. One thread per (b,n,d); 1-chunk prefetch.
__global__ __launch_bounds__(256)
void scan_carry_kernel(float* __restrict__ hloc, const float* __restrict__ totdt,
                       const float* __restrict__ A_log) {
  const int tid = blockIdx.x * 256 + threadIdx.x;   // NB*DSTATE*DI
  const int d = tid & (DI - 1);
  const int n = (tid >> 11) & 15;
  const int b = tid >> 15;
  const float An = -__expf(A_log[(size_t)d * DSTATE + n]);
  float h = 0.f;
  float le = hloc[((size_t)(b * CHUNKS) * DSTATE + n) * DI + d];
  float td = totdt[(size_t)(b * CHUNKS) * DI + d];
  for (int c = 0; c < CHUNKS; ++c) {
    const size_t ix = ((size_t)(b * CHUNKS + c) * DSTATE + n) * DI + d;
    float nle = 0.f, ntd = 0.f;
    if (c + 1 < CHUNKS) {
      nle = hloc[ix + (size_t)DSTATE * DI];
      ntd = totdt[(size_t)(b * CHUNKS + c + 1) * DI + d];
    }
    hloc[ix] = h;
    h = fmaf(__expf(An * td), h, le);
    le = nle; td = ntd;
  }
}

// Pass 3: correction + epilogue.  hloc layout [b][c][n][d].
__global__ __launch_bounds__(256)
void scan_fix_kernel(const float* __restrict__ xc2, const float* __restrict__ dtb,
                     const float* __restrict__ xp, const float* __restrict__ zbuf,
                     const float* __restrict__ A_log, const float* __restrict__ Dp,
                     const float* __restrict__ hloc, float* __restrict__ y) {
  __shared__ float sA[256 * DSTATE];
  const int tid = threadIdx.x;
  const int idx = blockIdx.x * 256 + tid;
  const int d = idx & (DI - 1);
  const int l = (idx >> 11) & (LSEQ - 1);
  const int b = idx >> 22;
  const int d0 = (blockIdx.x & ((DI / 256) - 1)) * 256;
  for (int i = tid; i < 256 * DSTATE; i += 256)
    sA[i] = -__expf(A_log[(size_t)d0 * DSTATE + i]);
  __syncthreads();

  const int c = l / LC;
  const float cum = dtb[idx];
  const float* hp = hloc + ((size_t)(b * CHUNKS + c)) * DSTATE * DI + d;
  const float4* Ct4 = (const float4*)&xp[((size_t)b * LSEQ + l) * NXP + DTRANK + DSTATE];
  const float* Ar = &sA[(d - d0) * DSTATE];
  float Ct[DSTATE];
  #pragma unroll
  for (int q = 0; q < 4; ++q) {
    const float4 cv = Ct4[q];
    Ct[4*q+0] = cv.x; Ct[4*q+1] = cv.y; Ct[4*q+2] = cv.z; Ct[4*q+3] = cv.w;
  }
  float corr = 0.f;
  #pragma unroll
  for (int n = 0; n < DSTATE; ++n)
    corr = fmaf(__expf(Ar[n] * cum) * hp[(size_t)n * DI], Ct[n], corr);
  const float xv = xc2[idx], zv = zbuf[idx];
  y[idx] = (y[idx] + corr + xv * Dp[d]) * silu_f(zv);
}

extern "C" void kernel_launch(void* const* d_in, const int* in_sizes, int n_in,
                              void* d_out, int out_size, void* d_ws, size_t ws_size,
                              hipStream_t stream) {
  const float* x      = (const float*)d_in[0];
  const float* W_in   = (const float*)d_in[1];
  const float* conv_w = (const float*)d_in[2];
  const float* conv_b = (const float*)d_in[3];
  const float* W_xproj= (const float*)d_in[4];
  const float* W_dt   = (const float*)d_in[5];
  const float* b_dt   = (const float*)d_in[6];
  const float* A_log  = (const float*)d_in[7];
  const float* Dp     = (const float*)d_in[8];
  const float* W_out  = (const float*)d_in[9];
  float* out = (float*)d_out;
  float* ws  = (float*)d_ws;

  // ws layout (floats), ~154 MB:
  //   xc_raw[SEG] | zbuf[SEG] | xc2[SEG] | dtb[SEG] | xp | hloc | totdt | Wo/Wd pools
  // Overlays (time-disjoint):
  //   Whi/Wlo over dtb    — consumed by GEMM1; dtb first written by GEMM3.
  //   xhi/xlo over xc2    — written by prep, read by GEMM1; xc2 written by conv after.
  //   y reuses xc_raw.
  const size_t SEG = (size_t)NB * LSEQ * DI;            // 8,388,608
  float* xc_raw = ws;
  float* zbuf   = ws + SEG;
  float* xc2    = ws + 2 * SEG;
  float* dtb    = ws + 3 * SEG;
  float* xp     = ws + 4 * SEG;                         // 393,216
  float* hloc   = xp + (size_t)MROWS * NXP;             // 2,097,152
  float* totdt  = hloc + (size_t)NB * CHUNKS * DSTATE * DI;  // 131,072
  float* wpool  = totdt + (size_t)NB * CHUNKS * DI;

  unsigned short* Whi = (unsigned short*)dtb;           // overlay (dead until GEMM3)
  unsigned short* Wlo = Whi + (size_t)2 * DI * DMODEL;

  unsigned short* xhi = (unsigned short*)xc2;           // overlay (dead until conv)
  unsigned short* xlo = xhi + (size_t)MROWS * DMODEL;

  unsigned short* Wohi = (unsigned short*)wpool;        // 2,097,152 ushort
  unsigned short* Wolo = Wohi + (size_t)DMODEL * DI;
  unsigned short* wdhi = Wolo + (size_t)DMODEL * DI;    // 131,072 ushort
  unsigned short* wdlo = wdhi + (size_t)DI * DTRANK;

  float* yb = xc_raw;
  dim3 blk(256);

  // Prep: weight + x splits, zero xp/out (one dispatch)
  const int prep_blocks = (2*DI*DMODEL/4 + DI*DTRANK/4 + DMODEL*DI/4
                           + MROWS*DMODEL/4 + MROWS*NXP/4 + MROWS*DMODEL/4) / 256;
  prep_kernel<<<prep_blocks, blk, 0, stream>>>(
      W_in, W_dt, W_out, x, Whi, Wlo, wdhi, wdlo, Wohi, Wolo, xhi, xlo, xp, out);

  // GEMM1 fused: [xc | z] = x @ W_in^T  (A pre-split; K=1024)
  gemm_a32_bf16x3<false,0,true><<<dim3(2*DI/128, MROWS/128, 1), blk, 0, stream>>>(
      nullptr, xhi, xlo, DMODEL, Whi, Wlo, nullptr, xc_raw, zbuf, DI, DMODEL, DMODEL);

  // conv + bias + SiLU (4 l per thread)
  conv_silu_kernel<<<(NB*(LSEQ/4)*DI)/256, blk, 0, stream>>>(xc_raw, conv_w, conv_b, xc2);

  // GEMM2: xp = xc2 @ W_xproj^T  (N=96) — split-K=8 fp32, atomic (xp zeroed in prep)
  gemm_nt_splitk<<<dim3(1, MROWS/128, 8), blk, 0, stream>>>(
      xc2, W_xproj, xp, NXP, DI, DI, NXP, DI/8);

  // GEMM3: dt = softplus(dt_lr @ W_dt^T + b_dt)  (A = xp[:, 0:64], lda=96, K=64)
  gemm_a32_bf16x3<false,1,false><<<dim3(DI/128, MROWS/128, 1), blk, 0, stream>>>(
      xp, nullptr, nullptr, NXP, wdhi, wdlo, b_dt, dtb, dtb, DI, DTRANK, DTRANK);

  // Chunked scan -> yb
  scan_chunk_kernel<<<dim3(DI/256, NB, CHUNKS), blk, 0, stream>>>(
      xc2, dtb, xp, A_log, yb, hloc, totdt);
  scan_carry_kernel<<<(NB*DI*DSTATE)/256, blk, 0, stream>>>(hloc, totdt, A_log);
  scan_fix_kernel<<<(NB*LSEQ*DI)/256, blk, 0, stream>>>(
      xc2, dtb, xp, zbuf, A_log, Dp, hloc, yb);

  // GEMM4: out = y @ W_out^T — A=y fp32 in-kernel split; split-K=2, atomic
  // (out zeroed in prep)
  gemm_a32_bf16x3<true,0,false><<<dim3(DMODEL/128, MROWS/128, 2), blk, 0, stream>>>(
      yb, nullptr, nullptr, DI, Wohi, Wolo, nullptr, out, out, DMODEL, DI, DI/2);
}